// Round 10
// baseline (72.947 us; speedup 1.0000x reference)
//
#include <hip/hip_runtime.h>

// MPO/TT embedding, single kernel, one block per token.
// out[t] = A2[h] (16x64) . B3[l] (64x48), everything recomputed per block in LDS.
// cores: c0 (1,8,4,32) c1 (32,8,4,64) c2 (64,8,4,64) c3 (64,8,4,24) c4 (24,8,3,1)
// v = token id; h = v>>9 (i1=h>>3,i2=h&7); l = v&511 (i3=l>>6, l2=l&63, i4=l2>>3, i5=l2&7)
// o = o12*48 + o345 ; o12 = o1*4+o2 (16) ; o345 = o3*12+o4*3+o5 (48); jj = o345/3 (16)
//
// Rationale (R6 post-mortem): two-kernel version paid a dependent-dispatch
// boundary = per-XCD L2 writeback+invalidate, then re-fetched B3p ~3x across
// XCDs (FETCH 26MB for 10MB unique). Recomputing B3/A2 per block trades ~2.5x
// VALU (fed from L2-resident 1MB cores) for zero intermediate traffic, zero
// flush, one launch.
__global__ __launch_bounds__(256) void k_single(const int* __restrict__ ids,
                                                const float* __restrict__ c0,
                                                const float* __restrict__ c1,
                                                const float* __restrict__ c2,
                                                const float* __restrict__ c3,
                                                const float* __restrict__ c4,
                                                float* __restrict__ out) {
    const int t = threadIdx.x;
    const int token = blockIdx.x;

    const int v = ids[token];
    const int h = v >> 9, l = v & 511;
    const int i1 = h >> 3, i2 = h & 7;
    const int i3 = l >> 6, l2 = l & 63;
    const int i4 = l2 >> 3, i5 = l2 & 7;

    __shared__ float B4s[64 * 12];       // [r3][o45]            3 KB
    __shared__ float B3s[64 * 16 * 4];   // [r2][jj][{3,pad}]   16 KB
    __shared__ float A2s[16 * 68];       // [o12][r2] pad 68    4.25 KB

    // ---- phase 1: B4s[r3][o45] = sum_r4 c3[r3,i4,o4,r4] * c4[r4,i5,o5] ----
    {
        int r3 = t >> 2, m = t & 3;      // m = o4
        const float* c3p = c3 + r3 * 768 + i4 * 96 + m * 24;  // [r3][i4][o4=m][r4]
        const float* c4p = c4 + i5 * 3;                       // [r4][i5][o5]
        float a0 = 0.f, a1 = 0.f, a2 = 0.f;
#pragma unroll
        for (int r4q = 0; r4q < 24; r4q += 4) {
            float4 cv = *reinterpret_cast<const float4*>(c3p + r4q);
            float cc[4] = {cv.x, cv.y, cv.z, cv.w};
#pragma unroll
            for (int d = 0; d < 4; ++d) {
                const float* bb = c4p + (r4q + d) * 24;
                a0 += cc[d] * bb[0];
                a1 += cc[d] * bb[1];
                a2 += cc[d] * bb[2];
            }
        }
        float* o = B4s + r3 * 12 + m * 3;
        o[0] = a0; o[1] = a1; o[2] = a2;
    }

    // ---- phase 1b (independent of B4s): A2s[o12][r2] ----
    // thread: o12 = t>>4, rq = (t&15)*4 ; 128 FMA
    {
        int o12 = t >> 4, rq = (t & 15) * 4;
        int o1 = o12 >> 2, o2 = o12 & 3;
        const float* c0r = c0 + i1 * 128 + o1 * 32;          // [i1][o1][r1]
        const float* c1p = c1 + (i2 * 4 + o2) * 64 + rq;     // + r1*2048
        float sx = 0.f, sy = 0.f, sz = 0.f, sw = 0.f;
#pragma unroll
        for (int r1 = 0; r1 < 32; ++r1) {
            float a = c0r[r1];
            float4 cv = *reinterpret_cast<const float4*>(c1p + r1 * 2048);
            sx += a * cv.x; sy += a * cv.y; sz += a * cv.z; sw += a * cv.w;
        }
        *reinterpret_cast<float4*>(A2s + o12 * 68 + rq) = make_float4(sx, sy, sz, sw);
    }
    __syncthreads();

    // ---- phase 2: B3s[r2][jj][.] = sum_r3 c2[r2,i3,o3,r3] * B4s[r3][.] ----
    {
        int r2 = t >> 2, q = t & 3;      // q = o3
        const float* c2p = c2 + r2 * 2048 + i3 * 256 + q * 64;   // + r3
        const float4* b4p = reinterpret_cast<const float4*>(B4s);
        float acc[4][3] = {};
#pragma unroll 4
        for (int r3q = 0; r3q < 64; r3q += 4) {
            float4 cv = *reinterpret_cast<const float4*>(c2p + r3q);
            float cc[4] = {cv.x, cv.y, cv.z, cv.w};
#pragma unroll
            for (int d = 0; d < 4; ++d) {
                float4 b0 = b4p[(r3q + d) * 3 + 0];
                float4 b1 = b4p[(r3q + d) * 3 + 1];
                float4 b2 = b4p[(r3q + d) * 3 + 2];
                float a = cc[d];
                acc[0][0] += a * b0.x; acc[0][1] += a * b0.y; acc[0][2] += a * b0.z;
                acc[1][0] += a * b0.w; acc[1][1] += a * b1.x; acc[1][2] += a * b1.y;
                acc[2][0] += a * b1.z; acc[2][1] += a * b1.w; acc[2][2] += a * b2.x;
                acc[3][0] += a * b2.y; acc[3][1] += a * b2.z; acc[3][2] += a * b2.w;
            }
        }
        float4* o = reinterpret_cast<float4*>(B3s) + (r2 * 16 + q * 4);
#pragma unroll
        for (int g = 0; g < 4; ++g)
            o[g] = make_float4(acc[g][0], acc[g][1], acc[g][2], 0.f);
    }
    __syncthreads();

    // ---- phase 3: GEMM  out[o12*48 + 3w + c] = sum_r2 A2s[o12][r2]*B3s[r2][w][c]
    {
        int o12 = t >> 4, w = t & 15;
        const float* arow = A2s + o12 * 68;
        const float4* b3 = reinterpret_cast<const float4*>(B3s) + w;
        float acc0 = 0.f, acc1 = 0.f, acc2 = 0.f;
#pragma unroll 4
        for (int r2q = 0; r2q < 64; r2q += 4) {
            float4 av = *reinterpret_cast<const float4*>(arow + r2q);
            float aa[4] = {av.x, av.y, av.z, av.w};
#pragma unroll
            for (int d = 0; d < 4; ++d) {
                float4 bv = b3[(r2q + d) * 16];
                acc0 += aa[d] * bv.x;
                acc1 += aa[d] * bv.y;
                acc2 += aa[d] * bv.z;
            }
        }
        float* o = out + (size_t)token * 768 + o12 * 48 + w * 3;
        o[0] = acc0; o[1] = acc1; o[2] = acc2;
    }
}

extern "C" void kernel_launch(void* const* d_in, const int* in_sizes, int n_in,
                              void* d_out, int out_size, void* d_ws, size_t ws_size,
                              hipStream_t stream) {
    const int*   ids = (const int*)d_in[0];
    const float* c0  = (const float*)d_in[1];
    const float* c1  = (const float*)d_in[2];
    const float* c2  = (const float*)d_in[3];
    const float* c3  = (const float*)d_in[4];
    const float* c4  = (const float*)d_in[5];
    float* out = (float*)d_out;

    int n_tokens = in_sizes[0];   // 8*512 = 4096

    k_single<<<n_tokens, 256, 0, stream>>>(ids, c0, c1, c2, c3, c4, out);
}

// Round 11
// 44.180 us; speedup vs baseline: 1.6511x; 1.6511x over previous
//
#include <hip/hip_runtime.h>

// MPO/TT embedding: out[t] = A2[h(t)] (16x64) . B3[l(t)] (64x48)
// cores: c0 (1,8,4,32) c1 (32,8,4,64) c2 (64,8,4,64) c3 (64,8,4,24) c4 (24,8,3,1)
// v = token id; h = v>>9 (i1=h>>3,i2=h&7); l = v&511 (i3=l>>6, l2=l&63, i4=l2>>3, i5=l2&7)
// o = o12*48 + o345 ; o12 = o1*4+o2 (16) ; o345 = o3*12+o4*3+o5 (48); jj = o345/3 (16)
//
// R10 post-mortem: per-token B3p tile re-fetch (82 MB unique from L3) was the
// k_main limiter. This version groups tokens by l (parity-split for occupancy):
// B3[l] slice loaded ONCE into registers per block, reused for all its tokens.

// ---- prep (unchanged, validated R4/R5): B3p quarters + A2T ----
__global__ __launch_bounds__(256) void k_prep(const float* __restrict__ c0,
                                              const float* __restrict__ c1,
                                              const float* __restrict__ c2,
                                              const float* __restrict__ c3,
                                              const float* __restrict__ c4,
                                              float* __restrict__ A2T,
                                              float* __restrict__ B3p) {
    const int t = threadIdx.x;
    const int b = blockIdx.x;

    if (b >= 2048) {
        int h = b - 2048;
        int r2 = t >> 2, o1 = t & 3;
        int i1 = h >> 3, i2 = h & 7;
        const float* c0p = c0 + i1 * 128 + o1 * 32;   // [i1][o1][r1]
        const float* c1p = c1 + i2 * 256 + r2;        // + r1*2048 + o2*64
        float a0 = 0.f, a1 = 0.f, a2 = 0.f, a3 = 0.f;
#pragma unroll
        for (int r1 = 0; r1 < 32; ++r1) {
            float a = c0p[r1];
            const float* p = c1p + r1 * 2048;
            a0 += a * p[0];
            a1 += a * p[64];
            a2 += a * p[128];
            a3 += a * p[192];
        }
        reinterpret_cast<float4*>(A2T)[(h * 64 + r2) * 4 + o1] =
            make_float4(a0, a1, a2, a3);
        return;
    }

    const int l = b >> 2, p = b & 3;
    const int i3 = l >> 6, l2 = l & 63;
    const int i4 = l2 >> 3, i5 = l2 & 7;

    __shared__ float B4s[64 * 12];   // [r3][o45]
    {
        int r3 = t >> 2, m = t & 3;  // m = o4
        const float* c3p = c3 + r3 * 768 + i4 * 96 + m * 24;
        const float* c4p = c4 + i5 * 3;
        float a0 = 0.f, a1 = 0.f, a2 = 0.f;
#pragma unroll
        for (int r4q = 0; r4q < 24; r4q += 4) {
            float4 cv = *reinterpret_cast<const float4*>(c3p + r4q);
            float cc[4] = {cv.x, cv.y, cv.z, cv.w};
#pragma unroll
            for (int d = 0; d < 4; ++d) {
                const float* bb = c4p + (r4q + d) * 24;
                a0 += cc[d] * bb[0];
                a1 += cc[d] * bb[1];
                a2 += cc[d] * bb[2];
            }
        }
        float* o = B4s + r3 * 12 + m * 3;
        o[0] = a0; o[1] = a1; o[2] = a2;
    }
    __syncthreads();

    {
        int r2 = 16 * p + (t >> 4);
        int jj = t & 15;
        int o3 = jj >> 2, g = jj & 3;
        const float* c2p = c2 + r2 * 2048 + i3 * 256 + o3 * 64;  // + r3
        float a0 = 0.f, a1 = 0.f, a2 = 0.f;
#pragma unroll
        for (int r3q = 0; r3q < 64; r3q += 4) {
            float4 cv = *reinterpret_cast<const float4*>(c2p + r3q);
            float cc[4] = {cv.x, cv.y, cv.z, cv.w};
#pragma unroll
            for (int d = 0; d < 4; ++d) {
                const float* bb = B4s + (r3q + d) * 12 + 3 * g;
                a0 += cc[d] * bb[0];
                a1 += cc[d] * bb[1];
                a2 += cc[d] * bb[2];
            }
        }
        reinterpret_cast<float4*>(B3p)[(l * 64 + r2) * 16 + jj] =
            make_float4(a0, a1, a2, 0.f);
    }
}

// ---- main: block = (l, token parity). B3[l] slice in registers, reused. ----
// thread t: rp = t>>6 (r2 quarter), q = (t>>4)&3 (o12 quad), jj = t&15
#define MAX_TOK 96
__global__ __launch_bounds__(256) void k_main(const int* __restrict__ ids,
                                              const float* __restrict__ A2T,
                                              const float* __restrict__ B3p,
                                              float* __restrict__ out,
                                              int n_tokens) {
    __shared__ float s[4 * 784];       // [rp][768+16]
    __shared__ int   s_list[MAX_TOK];
    __shared__ int   s_cnt;

    const int t = threadIdx.x;
    const int l   = blockIdx.x >> 1;
    const int par = blockIdx.x & 1;
    const int rp = t >> 6;
    const int lane = t & 63;
    const int q = lane >> 4, jj = lane & 15;

    if (t == 0) s_cnt = 0;
    __syncthreads();

    // scan & bucket (ids = 16 KB, L2-resident)
    for (int i = t; i < n_tokens; i += 256) {
        int v = ids[i];
        if ((v & 511) == l && (i & 1) == par) {
            int p = atomicAdd(&s_cnt, 1);
            if (p < MAX_TOK) s_list[p] = (i << 6) | (v >> 9);
        }
    }

    // preload this block's B3 slice into registers (16 float4 = 64 VGPR)
    const float4* Bbase = reinterpret_cast<const float4*>(B3p) +
                          (l * 64 + rp * 16) * 16 + jj;
    float4 Breg[16];
#pragma unroll
    for (int r = 0; r < 16; ++r) Breg[r] = Bbase[r * 16];

    __syncthreads();
    const int cnt = s_cnt;

    for (int k = 0; k < cnt; ++k) {
        int e = s_list[k];
        int token = e >> 6, h = e & 63;

        const float4* Ap = reinterpret_cast<const float4*>(A2T) +
                           (h * 64 + rp * 16) * 4 + q;
        float acc[4][3] = {};
#pragma unroll
        for (int r = 0; r < 16; ++r) {
            float4 a = Ap[r * 4];
            float4 b = Breg[r];
            acc[0][0] += a.x * b.x; acc[0][1] += a.x * b.y; acc[0][2] += a.x * b.z;
            acc[1][0] += a.y * b.x; acc[1][1] += a.y * b.y; acc[1][2] += a.y * b.z;
            acc[2][0] += a.z * b.x; acc[2][1] += a.z * b.y; acc[2][2] += a.z * b.z;
            acc[3][0] += a.w * b.x; acc[3][1] += a.w * b.y; acc[3][2] += a.w * b.z;
        }

        float* sp = s + rp * 784 + q * 192 + jj * 3;
#pragma unroll
        for (int qq = 0; qq < 4; ++qq) {
            sp[qq * 48 + 0] = acc[qq][0];
            sp[qq * 48 + 1] = acc[qq][1];
            sp[qq * 48 + 2] = acc[qq][2];
        }
        __syncthreads();

        if (t < 192) {
            const float4* s4 = reinterpret_cast<const float4*>(s);  // 196 f4/plane
            float4 v0 = s4[t];
            float4 v1 = s4[196 + t];
            float4 v2 = s4[392 + t];
            float4 v3 = s4[588 + t];
            float4 r;
            r.x = (v0.x + v1.x) + (v2.x + v3.x);
            r.y = (v0.y + v1.y) + (v2.y + v3.y);
            r.z = (v0.z + v1.z) + (v2.z + v3.z);
            r.w = (v0.w + v1.w) + (v2.w + v3.w);
            reinterpret_cast<float4*>(out + (size_t)token * 768)[t] = r;
        }
        __syncthreads();   // protect s before next token overwrites
    }
}

extern "C" void kernel_launch(void* const* d_in, const int* in_sizes, int n_in,
                              void* d_out, int out_size, void* d_ws, size_t ws_size,
                              hipStream_t stream) {
    const int*   ids = (const int*)d_in[0];
    const float* c0  = (const float*)d_in[1];
    const float* c1  = (const float*)d_in[2];
    const float* c2  = (const float*)d_in[3];
    const float* c3  = (const float*)d_in[4];
    const float* c4  = (const float*)d_in[5];
    float* out = (float*)d_out;

    char* ws = (char*)d_ws;
    float* A2T = (float*)(ws + 0);          // 262144 B
    float* B3p = (float*)(ws + 262144);     // 8388608 B (total ~8.6 MB)

    int n_tokens = in_sizes[0];             // 8*512 = 4096

    k_prep<<<2112, 256, 0, stream>>>(c0, c1, c2, c3, c4, A2T, B3p);
    k_main<<<1024, 256, 0, stream>>>(ids, A2T, B3p, out, n_tokens);
}

// Round 12
// 32.758 us; speedup vs baseline: 2.2268x; 1.3487x over previous
//
#include <hip/hip_runtime.h>

// MPO/TT embedding: out[t] = A2[h(t)] (16x64) . B3[l(t)] (64x48)
// cores: c0 (1,8,4,32) c1 (32,8,4,64) c2 (64,8,4,64) c3 (64,8,4,24) c4 (24,8,3,1)
// v = token id; h = v>>9 (i1=h>>3,i2=h&7); l = v&511 (i3=l>>6, l2=l&63, i4=l2>>3, i5=l2&7)
// o = o12*48 + o345 ; o12 = o1*4+o2 (16) ; o345 = o3*12+o4*3+o5 (48); jj = o345/3 (16)
//
// R11 change: B3p stored as bf16 (r2-pair interleaved, 8B per (r2,jj) triplet):
//   B3pb[l][ri][jj][8 shorts] = {r2=2ri: b0,b1,b2,pad ; r2=2ri+1: b0,b1,b2,pad}
// Halves the one large cold stream (8.4->4.2 MB write+read) and halves k_main's
// B-load instruction count. A2T stays f32 (256KB, L2-hot, broadcast reads).

__device__ __forceinline__ unsigned short f2bf(float x) {
    unsigned u = __float_as_uint(x);
    unsigned r = (u + 0x7FFFu + ((u >> 16) & 1u)) >> 16;   // RNE
    return (unsigned short)r;
}

// ---- prep: 2048 B3 quarter-blocks + 64 A2T blocks ----
__global__ __launch_bounds__(256) void k_prep(const float* __restrict__ c0,
                                              const float* __restrict__ c1,
                                              const float* __restrict__ c2,
                                              const float* __restrict__ c3,
                                              const float* __restrict__ c4,
                                              float* __restrict__ A2T,
                                              unsigned short* __restrict__ B3pb) {
    const int t = threadIdx.x;
    const int b = blockIdx.x;

    if (b >= 2048) {
        int h = b - 2048;
        int r2 = t >> 2, o1 = t & 3;
        int i1 = h >> 3, i2 = h & 7;
        const float* c0p = c0 + i1 * 128 + o1 * 32;   // [i1][o1][r1]
        const float* c1p = c1 + i2 * 256 + r2;        // + r1*2048 + o2*64
        float a0 = 0.f, a1 = 0.f, a2 = 0.f, a3 = 0.f;
#pragma unroll
        for (int r1 = 0; r1 < 32; ++r1) {
            float a = c0p[r1];
            const float* p = c1p + r1 * 2048;
            a0 += a * p[0];
            a1 += a * p[64];
            a2 += a * p[128];
            a3 += a * p[192];
        }
        reinterpret_cast<float4*>(A2T)[(h * 64 + r2) * 4 + o1] =
            make_float4(a0, a1, a2, a3);
        return;
    }

    const int l = b >> 2, p = b & 3;
    const int i3 = l >> 6, l2 = l & 63;
    const int i4 = l2 >> 3, i5 = l2 & 7;

    __shared__ float B4s[64 * 12];   // [r3][o45]
    {
        int r3 = t >> 2, m = t & 3;  // m = o4
        const float* c3p = c3 + r3 * 768 + i4 * 96 + m * 24;
        const float* c4p = c4 + i5 * 3;
        float a0 = 0.f, a1 = 0.f, a2 = 0.f;
#pragma unroll
        for (int r4q = 0; r4q < 24; r4q += 4) {
            float4 cv = *reinterpret_cast<const float4*>(c3p + r4q);
            float cc[4] = {cv.x, cv.y, cv.z, cv.w};
#pragma unroll
            for (int d = 0; d < 4; ++d) {
                const float* bb = c4p + (r4q + d) * 24;
                a0 += cc[d] * bb[0];
                a1 += cc[d] * bb[1];
                a2 += cc[d] * bb[2];
            }
        }
        float* o = B4s + r3 * 12 + m * 3;
        o[0] = a0; o[1] = a1; o[2] = a2;
    }
    __syncthreads();

    {
        int r2 = 16 * p + (t >> 4);
        int jj = t & 15;
        int o3 = jj >> 2, g = jj & 3;
        const float* c2p = c2 + r2 * 2048 + i3 * 256 + o3 * 64;  // + r3
        float a0 = 0.f, a1 = 0.f, a2 = 0.f;
#pragma unroll
        for (int r3q = 0; r3q < 64; r3q += 4) {
            float4 cv = *reinterpret_cast<const float4*>(c2p + r3q);
            float cc[4] = {cv.x, cv.y, cv.z, cv.w};
#pragma unroll
            for (int d = 0; d < 4; ++d) {
                const float* bb = B4s + (r3q + d) * 12 + 3 * g;
                a0 += cc[d] * bb[0];
                a1 += cc[d] * bb[1];
                a2 += cc[d] * bb[2];
            }
        }
        // bf16 pack: [l][ri=r2>>1][jj][ (r2&1)*4 .. +3 ]
        unsigned short* o = B3pb +
            (((size_t)(l * 32 + (r2 >> 1)) * 16 + jj) * 8 + (r2 & 1) * 4);
        *reinterpret_cast<ushort4*>(o) =
            make_ushort4(f2bf(a0), f2bf(a1), f2bf(a2), 0);
    }
}

// ---- main: one block per token (R5 skeleton), bf16 B-loads ----
// thread t: rp = t>>6 (r2 quarter), q = (t>>4)&3 (o12 quad), jj = t&15
__global__ __launch_bounds__(256) void k_main(const int* __restrict__ ids,
                                              const float* __restrict__ A2T,
                                              const unsigned short* __restrict__ B3pb,
                                              float* __restrict__ out) {
    __shared__ float s[4 * 784];           // [rp][768+16]
    const int token = blockIdx.x;
    const int t = threadIdx.x;
    const int rp = t >> 6;
    const int lane = t & 63;
    const int q = lane >> 4, jj = lane & 15;

    const int v = ids[token];
    const int h = v >> 9, l = v & 511;

    const float4* Ap = reinterpret_cast<const float4*>(A2T) + (h * 64 + rp * 16) * 4 + q;
    const uint4*  Bp = reinterpret_cast<const uint4*>(B3pb) + ((size_t)(l * 32 + rp * 8)) * 16 + jj;

    float acc[4][3] = {};
#pragma unroll
    for (int ri = 0; ri < 8; ++ri) {
        uint4  bv = Bp[ri * 16];
        float4 a0 = Ap[(2 * ri) * 4];
        float4 a1 = Ap[(2 * ri + 1) * 4];
        // r2 = 2ri (even): triplet in bv.x (lo,hi), bv.y (lo)
        float be0 = __uint_as_float(bv.x << 16);
        float be1 = __uint_as_float(bv.x & 0xFFFF0000u);
        float be2 = __uint_as_float(bv.y << 16);
        // r2 = 2ri+1 (odd): triplet in bv.z (lo,hi), bv.w (lo)
        float bo0 = __uint_as_float(bv.z << 16);
        float bo1 = __uint_as_float(bv.z & 0xFFFF0000u);
        float bo2 = __uint_as_float(bv.w << 16);

        acc[0][0] += a0.x * be0; acc[0][1] += a0.x * be1; acc[0][2] += a0.x * be2;
        acc[1][0] += a0.y * be0; acc[1][1] += a0.y * be1; acc[1][2] += a0.y * be2;
        acc[2][0] += a0.z * be0; acc[2][1] += a0.z * be1; acc[2][2] += a0.z * be2;
        acc[3][0] += a0.w * be0; acc[3][1] += a0.w * be1; acc[3][2] += a0.w * be2;

        acc[0][0] += a1.x * bo0; acc[0][1] += a1.x * bo1; acc[0][2] += a1.x * bo2;
        acc[1][0] += a1.y * bo0; acc[1][1] += a1.y * bo1; acc[1][2] += a1.y * bo2;
        acc[2][0] += a1.z * bo0; acc[2][1] += a1.z * bo1; acc[2][2] += a1.z * bo2;
        acc[3][0] += a1.w * bo0; acc[3][1] += a1.w * bo1; acc[3][2] += a1.w * bo2;
    }

    float* sp = s + rp * 784 + q * 192 + jj * 3;
#pragma unroll
    for (int qq = 0; qq < 4; ++qq) {
        sp[qq * 48 + 0] = acc[qq][0];
        sp[qq * 48 + 1] = acc[qq][1];
        sp[qq * 48 + 2] = acc[qq][2];
    }
    __syncthreads();

    if (t < 192) {
        const float4* s4 = reinterpret_cast<const float4*>(s);  // 196 f4/plane
        float4 v0 = s4[t];
        float4 v1 = s4[196 + t];
        float4 v2 = s4[392 + t];
        float4 v3 = s4[588 + t];
        float4 r;
        r.x = (v0.x + v1.x) + (v2.x + v3.x);
        r.y = (v0.y + v1.y) + (v2.y + v3.y);
        r.z = (v0.z + v1.z) + (v2.z + v3.z);
        r.w = (v0.w + v1.w) + (v2.w + v3.w);
        reinterpret_cast<float4*>(out + (size_t)token * 768)[t] = r;
    }
}

extern "C" void kernel_launch(void* const* d_in, const int* in_sizes, int n_in,
                              void* d_out, int out_size, void* d_ws, size_t ws_size,
                              hipStream_t stream) {
    const int*   ids = (const int*)d_in[0];
    const float* c0  = (const float*)d_in[1];
    const float* c1  = (const float*)d_in[2];
    const float* c2  = (const float*)d_in[3];
    const float* c3  = (const float*)d_in[4];
    const float* c4  = (const float*)d_in[5];
    float* out = (float*)d_out;

    char* ws = (char*)d_ws;
    float* A2T = (float*)(ws + 0);                       // 262144 B
    unsigned short* B3pb = (unsigned short*)(ws + 262144); // 4194304 B (total ~4.5 MB)

    int n_tokens = in_sizes[0];             // 8*512 = 4096

    k_prep<<<2112, 256, 0, stream>>>(c0, c1, c2, c3, c4, A2T, B3pb);
    k_main<<<n_tokens, 256, 0, stream>>>(ids, A2T, B3pb, out);
}

// Round 13
// 25.920 us; speedup vs baseline: 2.8143x; 1.2638x over previous
//
#include <hip/hip_runtime.h>

// MPO/TT embedding: out[t] = A2[h(t)] (16x64) . B3[l(t)] (64x48), MFMA edition.
// cores: c0 (1,8,4,32) c1 (32,8,4,64) c2 (64,8,4,64) c3 (64,8,4,24) c4 (24,8,3,1)
// v = token id; h = v>>9 (i1=h>>3,i2=h&7); l = v&511 (i3=l>>6, l2=l&63, i4=l2>>3, i5=l2&7)
// o = o12*48 + o345 ; o12 = o1*4+o2 (16, =M) ; o345 = o3*12+o4*3+o5 (48, =N); r2 = K (64)
//
// R13: per-token GEMM via v_mfma_f32_16x16x32_bf16 (6 MFMA/token: 3 N-tiles x 2 K-steps).
// k_prep writes both intermediates in MFMA fragment order, bf16:
//   A-frag (M=16,K=32): lane = (k_in>>3)*16 + m, holds k j=0..7 (k = ks*32 + (lane>>4)*8 + j)
//   B-frag (K=32,N=16): lane = (k_in>>3)*16 + n, same k packing
//   A2Tb[h][ks][lane][j]            : 64*2*64*8 bf16 = 128 KB
//   B3pb[l][nt][ks][lane][j]        : 512*3*2*64*8 bf16 = 3 MB (no padding)
// C/D layout (HW-verified m89): col(n)=lane&15, row(m)=(lane>>4)*4+reg.

typedef __attribute__((ext_vector_type(8))) short bf16x8;
typedef __attribute__((ext_vector_type(4))) float f32x4;

__device__ __forceinline__ unsigned short f2bf(float x) {
    unsigned u = __float_as_uint(x);
    unsigned r = (u + 0x7FFFu + ((u >> 16) & 1u)) >> 16;   // RNE
    return (unsigned short)r;
}

// ---- prep: 2048 B3 quarter-blocks + 64 A2T blocks ----
__global__ __launch_bounds__(256) void k_prep(const float* __restrict__ c0,
                                              const float* __restrict__ c1,
                                              const float* __restrict__ c2,
                                              const float* __restrict__ c3,
                                              const float* __restrict__ c4,
                                              unsigned short* __restrict__ A2Tb,
                                              unsigned short* __restrict__ B3pb) {
    const int t = threadIdx.x;
    const int b = blockIdx.x;

    if (b >= 2048) {
        // ---- A2 for h = b-2048, packed as A-fragments ----
        if (t >= 128) return;
        int h = b - 2048;
        int i1 = h >> 3, i2 = h & 7;
        int m = t & 15, kc = t >> 4;            // kc in 0..7 ; r2 = kc*8 + j
        int o1 = m >> 2, o2 = m & 3;
        const float* c0r = c0 + i1 * 128 + o1 * 32;          // [i1][o1][r1]
        const float* c1p = c1 + i2 * 256 + o2 * 64 + kc * 8; // + r1*2048
        float s[8] = {};
#pragma unroll
        for (int r1 = 0; r1 < 32; ++r1) {
            float a = c0r[r1];
            float4 v0 = *reinterpret_cast<const float4*>(c1p + r1 * 2048);
            float4 v1 = *reinterpret_cast<const float4*>(c1p + r1 * 2048 + 4);
            s[0] += a * v0.x; s[1] += a * v0.y; s[2] += a * v0.z; s[3] += a * v0.w;
            s[4] += a * v1.x; s[5] += a * v1.y; s[6] += a * v1.z; s[7] += a * v1.w;
        }
        int ks = kc >> 2, lh = kc & 3;          // lane = lh*16 + m
        unsigned short* dst = A2Tb + (size_t)(((h * 2 + ks) * 64 + lh * 16 + m)) * 8;
        *reinterpret_cast<ushort4*>(dst) =
            make_ushort4(f2bf(s[0]), f2bf(s[1]), f2bf(s[2]), f2bf(s[3]));
        *reinterpret_cast<ushort4*>(dst + 4) =
            make_ushort4(f2bf(s[4]), f2bf(s[5]), f2bf(s[6]), f2bf(s[7]));
        return;
    }

    // ---- B3 quarter: l = b>>2, r2 in [16p, 16p+16) ----
    const int l = b >> 2, p = b & 3;
    const int i3 = l >> 6, l2 = l & 63;
    const int i4 = l2 >> 3, i5 = l2 & 7;

    __shared__ float B4s[64 * 12];   // [r3][o45]
    {
        int r3 = t >> 2, m = t & 3;  // m = o4
        const float* c3p = c3 + r3 * 768 + i4 * 96 + m * 24;
        const float* c4p = c4 + i5 * 3;
        float a0 = 0.f, a1 = 0.f, a2 = 0.f;
#pragma unroll
        for (int r4q = 0; r4q < 24; r4q += 4) {
            float4 cv = *reinterpret_cast<const float4*>(c3p + r4q);
            float cc[4] = {cv.x, cv.y, cv.z, cv.w};
#pragma unroll
            for (int d = 0; d < 4; ++d) {
                const float* bb = c4p + (r4q + d) * 24;
                a0 += cc[d] * bb[0];
                a1 += cc[d] * bb[1];
                a2 += cc[d] * bb[2];
            }
        }
        float* o = B4s + r3 * 12 + m * 3;
        o[0] = a0; o[1] = a1; o[2] = a2;
    }
    __syncthreads();

    {
        int r2 = 16 * p + (t >> 4);
        int jj = t & 15;
        int o3 = jj >> 2, g = jj & 3;
        const float* c2p = c2 + r2 * 2048 + i3 * 256 + o3 * 64;  // + r3
        float a0 = 0.f, a1 = 0.f, a2 = 0.f;
#pragma unroll
        for (int r3q = 0; r3q < 64; r3q += 4) {
            float4 cv = *reinterpret_cast<const float4*>(c2p + r3q);
            float cc[4] = {cv.x, cv.y, cv.z, cv.w};
#pragma unroll
            for (int d = 0; d < 4; ++d) {
                const float* bb = B4s + (r3q + d) * 12 + 3 * g;
                a0 += cc[d] * bb[0];
                a1 += cc[d] * bb[1];
                a2 += cc[d] * bb[2];
            }
        }
        // scatter into B-fragment layout: element (r2, o345=3jj+c)
        int ks = r2 >> 5, lh = (r2 >> 3) & 3, j = r2 & 7;
        unsigned short* bp = B3pb + (size_t)l * 3072;   // 6*64*8
        float av[3] = {a0, a1, a2};
#pragma unroll
        for (int c = 0; c < 3; ++c) {
            int o345 = 3 * jj + c;
            int nt = o345 >> 4, n = o345 & 15;
            bp[(size_t)(((nt * 2 + ks) * 64) + lh * 16 + n) * 8 + j] = f2bf(av[c]);
        }
    }
}

// ---- main: one wave per token, 6 MFMA ----
__global__ __launch_bounds__(256) void k_main(const int* __restrict__ ids,
                                              const unsigned short* __restrict__ A2Tb,
                                              const unsigned short* __restrict__ B3pb,
                                              float* __restrict__ out,
                                              int n_tokens) {
    const int t = threadIdx.x;
    const int wave = t >> 6, lane = t & 63;
    const int token = blockIdx.x * 4 + wave;
    if (token >= n_tokens) return;

    const int v = ids[token];
    const int h = v >> 9, l = v & 511;

    const bf16x8* A = reinterpret_cast<const bf16x8*>(A2Tb) + h * 128 + lane;
    const bf16x8* B = reinterpret_cast<const bf16x8*>(B3pb) + l * 384 + lane;

    bf16x8 a0 = A[0];
    bf16x8 a1 = A[64];
    f32x4 z = {0.f, 0.f, 0.f, 0.f};

    f32x4 acc0 = __builtin_amdgcn_mfma_f32_16x16x32_bf16(a0, B[0],   z, 0, 0, 0);
    acc0       = __builtin_amdgcn_mfma_f32_16x16x32_bf16(a1, B[64],  acc0, 0, 0, 0);
    f32x4 acc1 = __builtin_amdgcn_mfma_f32_16x16x32_bf16(a0, B[128], z, 0, 0, 0);
    acc1       = __builtin_amdgcn_mfma_f32_16x16x32_bf16(a1, B[192], acc1, 0, 0, 0);
    f32x4 acc2 = __builtin_amdgcn_mfma_f32_16x16x32_bf16(a0, B[256], z, 0, 0, 0);
    acc2       = __builtin_amdgcn_mfma_f32_16x16x32_bf16(a1, B[320], acc2, 0, 0, 0);

    // C/D: col = lane&15 (n within tile), row = (lane>>4)*4 + reg (= o12)
    const int n = lane & 15;
    float* o = out + (size_t)token * 768 + ((lane >> 4) * 4) * 48 + n;
#pragma unroll
    for (int reg = 0; reg < 4; ++reg) {
        o[reg * 48 + 0]  = acc0[reg];
        o[reg * 48 + 16] = acc1[reg];
        o[reg * 48 + 32] = acc2[reg];
    }
}

extern "C" void kernel_launch(void* const* d_in, const int* in_sizes, int n_in,
                              void* d_out, int out_size, void* d_ws, size_t ws_size,
                              hipStream_t stream) {
    const int*   ids = (const int*)d_in[0];
    const float* c0  = (const float*)d_in[1];
    const float* c1  = (const float*)d_in[2];
    const float* c2  = (const float*)d_in[3];
    const float* c3  = (const float*)d_in[4];
    const float* c4  = (const float*)d_in[5];
    float* out = (float*)d_out;

    char* ws = (char*)d_ws;
    unsigned short* A2Tb = (unsigned short*)(ws + 0);        // 131072 B
    unsigned short* B3pb = (unsigned short*)(ws + 131072);   // 3145728 B (~3.1 MB total)

    int n_tokens = in_sizes[0];             // 8*512 = 4096

    k_prep<<<2112, 256, 0, stream>>>(c0, c1, c2, c3, c4, A2Tb, B3pb);
    k_main<<<(n_tokens + 3) / 4, 256, 0, stream>>>(ids, A2Tb, B3pb, out, n_tokens);
}

// Round 14
// 24.894 us; speedup vs baseline: 2.9304x; 1.0412x over previous
//
#include <hip/hip_runtime.h>

// MPO/TT embedding: out[t] = A2[h(t)] (16x64) . B3[l(t)] (64x48), MFMA edition.
// cores: c0 (1,8,4,32) c1 (32,8,4,64) c2 (64,8,4,64) c3 (64,8,4,24) c4 (24,8,3,1)
// v = token id; h = v>>9 (i1=h>>3,i2=h&7); l = v&511 (i3=l>>6, l2=l&63, i4=l2>>3, i5=l2&7)
// o = o12*48 + o345 ; o12 = o1*4+o2 (16, =M) ; o345 = o3*12+o4*3+o5 (48, =N); r2 = K (64)
//
// R14: same dataflow/layout as R13 (validated), but k_prep's B3 store path is
// fixed: fragment-ordered values staged in LDS (1.5 KB/block), then written as
// 96 x 16B coalesced stores (3 contiguous 512B bursts) instead of 3x256
// scattered 2B stores per block.
//
// Fragment layouts (R13-validated on HW):
//   A-frag: lane = lh*16+m holds k = ks*32+lh*8+j, j=0..7
//   B-frag: lane = lh*16+n, same k packing
//   A2Tb[h][ks][lane][j] : 128 KB ; B3pb[l][nt][ks][lane][j] : 3 MB
//   C/D: col(n) = lane&15, row(m) = (lane>>4)*4+reg

typedef __attribute__((ext_vector_type(8))) short bf16x8;
typedef __attribute__((ext_vector_type(8))) unsigned short u16x8;
typedef __attribute__((ext_vector_type(4))) float f32x4;

__device__ __forceinline__ unsigned short f2bf(float x) {
    unsigned u = __float_as_uint(x);
    unsigned r = (u + 0x7FFFu + ((u >> 16) & 1u)) >> 16;   // RNE
    return (unsigned short)r;
}

// ---- prep: 2048 B3 quarter-blocks + 64 A2T blocks ----
__global__ __launch_bounds__(256) void k_prep(const float* __restrict__ c0,
                                              const float* __restrict__ c1,
                                              const float* __restrict__ c2,
                                              const float* __restrict__ c3,
                                              const float* __restrict__ c4,
                                              unsigned short* __restrict__ A2Tb,
                                              unsigned short* __restrict__ B3pb) {
    const int t = threadIdx.x;
    const int b = blockIdx.x;

    if (b >= 2048) {
        // ---- A2 for h = b-2048, packed as A-fragments ----
        if (t >= 128) return;
        int h = b - 2048;
        int i1 = h >> 3, i2 = h & 7;
        int m = t & 15, kc = t >> 4;            // kc in 0..7 ; r2 = kc*8 + j
        int o1 = m >> 2, o2 = m & 3;
        const float* c0r = c0 + i1 * 128 + o1 * 32;          // [i1][o1][r1]
        const float* c1p = c1 + i2 * 256 + o2 * 64 + kc * 8; // + r1*2048
        float s[8] = {};
#pragma unroll
        for (int r1 = 0; r1 < 32; ++r1) {
            float a = c0r[r1];
            float4 v0 = *reinterpret_cast<const float4*>(c1p + r1 * 2048);
            float4 v1 = *reinterpret_cast<const float4*>(c1p + r1 * 2048 + 4);
            s[0] += a * v0.x; s[1] += a * v0.y; s[2] += a * v0.z; s[3] += a * v0.w;
            s[4] += a * v1.x; s[5] += a * v1.y; s[6] += a * v1.z; s[7] += a * v1.w;
        }
        int ks = kc >> 2, lh = kc & 3;          // lane = lh*16 + m
        unsigned short* dst = A2Tb + (size_t)(((h * 2 + ks) * 64 + lh * 16 + m)) * 8;
        *reinterpret_cast<ushort4*>(dst) =
            make_ushort4(f2bf(s[0]), f2bf(s[1]), f2bf(s[2]), f2bf(s[3]));
        *reinterpret_cast<ushort4*>(dst + 4) =
            make_ushort4(f2bf(s[4]), f2bf(s[5]), f2bf(s[6]), f2bf(s[7]));
        return;
    }

    // ---- B3 quarter: l = b>>2, r2 in [16p, 16p+16) ----
    const int l = b >> 2, p = b & 3;
    const int i3 = l >> 6, l2 = l & 63;
    const int i4 = l2 >> 3, i5 = l2 & 7;
    const int ks = p >> 1, lh0 = (p & 1) * 2;   // this quarter's K-step / lane-half base

    __shared__ float B4s[64 * 12];        // [r3][o45]
    __shared__ unsigned short stg[768];   // [nt][lhrel][n][j] = [3][2][16][8]

    {
        int r3 = t >> 2, m = t & 3;  // m = o4
        const float* c3p = c3 + r3 * 768 + i4 * 96 + m * 24;
        const float* c4p = c4 + i5 * 3;
        float a0 = 0.f, a1 = 0.f, a2 = 0.f;
#pragma unroll
        for (int r4q = 0; r4q < 24; r4q += 4) {
            float4 cv = *reinterpret_cast<const float4*>(c3p + r4q);
            float cc[4] = {cv.x, cv.y, cv.z, cv.w};
#pragma unroll
            for (int d = 0; d < 4; ++d) {
                const float* bb = c4p + (r4q + d) * 24;
                a0 += cc[d] * bb[0];
                a1 += cc[d] * bb[1];
                a2 += cc[d] * bb[2];
            }
        }
        float* o = B4s + r3 * 12 + m * 3;
        o[0] = a0; o[1] = a1; o[2] = a2;
    }
    __syncthreads();

    {
        int r2l = t >> 4;                 // 0..15 within quarter; r2 = 16p + r2l
        int jj = t & 15;
        int r2 = 16 * p + r2l;
        int lhrel = r2l >> 3, j = r2l & 7;
        int o3 = jj >> 2, g = jj & 3;
        const float* c2p = c2 + r2 * 2048 + i3 * 256 + o3 * 64;  // + r3
        float a0 = 0.f, a1 = 0.f, a2 = 0.f;
#pragma unroll
        for (int r3q = 0; r3q < 64; r3q += 4) {
            float4 cv = *reinterpret_cast<const float4*>(c2p + r3q);
            float cc[4] = {cv.x, cv.y, cv.z, cv.w};
#pragma unroll
            for (int d = 0; d < 4; ++d) {
                const float* bb = B4s + (r3q + d) * 12 + 3 * g;
                a0 += cc[d] * bb[0];
                a1 += cc[d] * bb[1];
                a2 += cc[d] * bb[2];
            }
        }
        // stage in fragment order (LDS), then coalesced global write below
        float av[3] = {a0, a1, a2};
#pragma unroll
        for (int c = 0; c < 3; ++c) {
            int o345 = 3 * jj + c;
            int nt = o345 >> 4, n = o345 & 15;
            stg[nt * 256 + lhrel * 128 + n * 8 + j] = f2bf(av[c]);
        }
    }
    __syncthreads();

    if (t < 96) {
        // local linear u16 index = t*8 ; global = l*3072 + (nt*2+ks)*512 + lh0*128 + r
        int nt = t >> 5, r = (t & 31) * 8;
        u16x8 val = *reinterpret_cast<const u16x8*>(stg + t * 8);
        size_t dst = (size_t)l * 3072 + (size_t)(nt * 2 + ks) * 512 + lh0 * 128 + r;
        *reinterpret_cast<u16x8*>(B3pb + dst) = val;
    }
}

// ---- main: one wave per token, 6 MFMA (unchanged from R13) ----
__global__ __launch_bounds__(256) void k_main(const int* __restrict__ ids,
                                              const unsigned short* __restrict__ A2Tb,
                                              const unsigned short* __restrict__ B3pb,
                                              float* __restrict__ out,
                                              int n_tokens) {
    const int t = threadIdx.x;
    const int wave = t >> 6, lane = t & 63;
    const int token = blockIdx.x * 4 + wave;
    if (token >= n_tokens) return;

    const int v = ids[token];
    const int h = v >> 9, l = v & 511;

    const bf16x8* A = reinterpret_cast<const bf16x8*>(A2Tb) + h * 128 + lane;
    const bf16x8* B = reinterpret_cast<const bf16x8*>(B3pb) + l * 384 + lane;

    bf16x8 a0 = A[0];
    bf16x8 a1 = A[64];
    f32x4 z = {0.f, 0.f, 0.f, 0.f};

    f32x4 acc0 = __builtin_amdgcn_mfma_f32_16x16x32_bf16(a0, B[0],   z, 0, 0, 0);
    acc0       = __builtin_amdgcn_mfma_f32_16x16x32_bf16(a1, B[64],  acc0, 0, 0, 0);
    f32x4 acc1 = __builtin_amdgcn_mfma_f32_16x16x32_bf16(a0, B[128], z, 0, 0, 0);
    acc1       = __builtin_amdgcn_mfma_f32_16x16x32_bf16(a1, B[192], acc1, 0, 0, 0);
    f32x4 acc2 = __builtin_amdgcn_mfma_f32_16x16x32_bf16(a0, B[256], z, 0, 0, 0);
    acc2       = __builtin_amdgcn_mfma_f32_16x16x32_bf16(a1, B[320], acc2, 0, 0, 0);

    // C/D: col = lane&15 (n within tile), row = (lane>>4)*4 + reg (= o12)
    const int n = lane & 15;
    float* o = out + (size_t)token * 768 + ((lane >> 4) * 4) * 48 + n;
#pragma unroll
    for (int reg = 0; reg < 4; ++reg) {
        o[reg * 48 + 0]  = acc0[reg];
        o[reg * 48 + 16] = acc1[reg];
        o[reg * 48 + 32] = acc2[reg];
    }
}

extern "C" void kernel_launch(void* const* d_in, const int* in_sizes, int n_in,
                              void* d_out, int out_size, void* d_ws, size_t ws_size,
                              hipStream_t stream) {
    const int*   ids = (const int*)d_in[0];
    const float* c0  = (const float*)d_in[1];
    const float* c1  = (const float*)d_in[2];
    const float* c2  = (const float*)d_in[3];
    const float* c3  = (const float*)d_in[4];
    const float* c4  = (const float*)d_in[5];
    float* out = (float*)d_out;

    char* ws = (char*)d_ws;
    unsigned short* A2Tb = (unsigned short*)(ws + 0);        // 131072 B
    unsigned short* B3pb = (unsigned short*)(ws + 131072);   // 3145728 B (~3.1 MB total)

    int n_tokens = in_sizes[0];             // 8*512 = 4096

    k_prep<<<2112, 256, 0, stream>>>(c0, c1, c2, c3, c4, A2Tb, B3pb);
    k_main<<<(n_tokens + 3) / 4, 256, 0, stream>>>(ids, A2Tb, B3pb, out, n_tokens);
}